// Round 3
// baseline (507.969 us; speedup 1.0000x reference)
//
#include <hip/hip_runtime.h>
#include <hip/hip_bf16.h>

#define BB 4
#define NN 2048
#define DD 512
#define HH 8
#define DKK 64

typedef unsigned int u32;
typedef __attribute__((ext_vector_type(8))) short short8;    // 8 bf16 = 4 VGPRs
typedef __attribute__((ext_vector_type(16))) float f32x16;   // mfma 32x32 acc

// ---- bf16 split helpers (hi = rne(x), lo = rne(x - hi)) --------------------
__device__ __forceinline__ u32 pk_bf2(float a, float b) {
    union { __hip_bfloat162 h; u32 u; } cv;
    cv.h = __float22bfloat162_rn(make_float2(a, b));
    return cv.u;
}
__device__ __forceinline__ float2 upk_bf2(u32 w) {
    union { u32 u; __hip_bfloat162 h; } cv;
    cv.u = w;
    return __bfloat1622float2(cv.h);
}
__device__ __forceinline__ void split_pk(float a, float b, u32& hw, u32& lw) {
    hw = pk_bf2(a, b);
    float2 hf = upk_bf2(hw);
    lw = pk_bf2(a - hf.x, b - hf.y);
}

// ---------------------------------------------------------------------------
// Split-bf16 MFMA GEMM: C[M,512] = A[M,512] @ W[512,512] + bias
// 128x128 tile, BK=32, 4 waves (2x2), per-wave 64x64 = 2x2 frags of 32x32.
// Every fp32 product = 3 bf16 MFMAs (hi*hi + hi*lo + lo*hi).
// MODE 0: blockIdx.z selects (A,W,bias) from {q,k,v}; out = head-split (B,H,N,DK)
// MODE 1: plain row-major out (B*N, D)
// LDS: A natural [row][k] stride 40 ushort; W transposed [col][k] stride 40.
// ---------------------------------------------------------------------------
template<int MODE>
__global__ __launch_bounds__(256) void gemm_mfma(
    const float* __restrict__ A0, const float* __restrict__ A1, const float* __restrict__ A2,
    const float* __restrict__ W0, const float* __restrict__ W1, const float* __restrict__ W2,
    const float* __restrict__ B0, const float* __restrict__ B1, const float* __restrict__ B2,
    float* __restrict__ OutBase)
{
    __shared__ u32 AsH[128 * 20], AsL[128 * 20], WsH[128 * 20], WsL[128 * 20];

    const int tid  = threadIdx.x;
    const int lane = tid & 63;
    const int wid  = tid >> 6;
    const int g    = lane >> 5;      // half-wave
    const int lr   = lane & 31;
    const int wm   = wid >> 1, wn = wid & 1;
    const int m0 = blockIdx.x * 128, n0 = blockIdx.y * 128;
    const int z  = blockIdx.z;

    const float* A    = (z == 0) ? A0 : (z == 1) ? A1 : A2;
    const float* W    = (z == 0) ? W0 : (z == 1) ? W1 : W2;
    const float* bias = (z == 0) ? B0 : (z == 1) ? B1 : B2;
    float* Out = (MODE == 0) ? (OutBase + (size_t)z * ((size_t)BB * NN * DD)) : OutBase;

    f32x16 acc[2][2];
    #pragma unroll
    for (int i = 0; i < 2; ++i)
        #pragma unroll
        for (int j = 0; j < 2; ++j)
            #pragma unroll
            for (int r = 0; r < 16; ++r) acc[i][j][r] = 0.f;

    const int arow = tid >> 1, akc = (tid & 1) * 16;     // A staging map
    const int wcol = tid & 127, wkg = (tid >> 7) * 16;   // W staging map

    for (int k0 = 0; k0 < DD; k0 += 32) {
        __syncthreads();
        {   // stage A tile 128x32 (natural layout, bf16 hi/lo)
            const float* ap = &A[(size_t)(m0 + arow) * DD + k0 + akc];
            float f[16];
            *(float4*)&f[0]  = *(const float4*)&ap[0];
            *(float4*)&f[4]  = *(const float4*)&ap[4];
            *(float4*)&f[8]  = *(const float4*)&ap[8];
            *(float4*)&f[12] = *(const float4*)&ap[12];
            u32 hw[8], lw[8];
            #pragma unroll
            for (int j = 0; j < 8; ++j) split_pk(f[2*j], f[2*j+1], hw[j], lw[j]);
            const int base = arow * 20 + akc / 2;
            *(uint4*)&AsH[base]     = *(uint4*)&hw[0];
            *(uint4*)&AsH[base + 4] = *(uint4*)&hw[4];
            *(uint4*)&AsL[base]     = *(uint4*)&lw[0];
            *(uint4*)&AsL[base + 4] = *(uint4*)&lw[4];
        }
        {   // stage W tile 32x128 transposed -> Ws[col][k]
            float f[16];
            #pragma unroll
            for (int j = 0; j < 16; ++j)
                f[j] = W[(size_t)(k0 + wkg + j) * DD + n0 + wcol];
            u32 hw[8], lw[8];
            #pragma unroll
            for (int j = 0; j < 8; ++j) split_pk(f[2*j], f[2*j+1], hw[j], lw[j]);
            const int base = wcol * 20 + wkg / 2;
            *(uint4*)&WsH[base]     = *(uint4*)&hw[0];
            *(uint4*)&WsH[base + 4] = *(uint4*)&hw[4];
            *(uint4*)&WsL[base]     = *(uint4*)&lw[0];
            *(uint4*)&WsL[base + 4] = *(uint4*)&lw[4];
        }
        __syncthreads();

        #pragma unroll
        for (int c = 0; c < 2; ++c) {            // two K=16 chunks of BK=32
            short8 ah[2], al[2], bh[2], bl[2];
            #pragma unroll
            for (int i = 0; i < 2; ++i) {
                const int off = (wm * 64 + i * 32 + lr) * 20 + c * 8 + g * 4;
                ah[i] = *(const short8*)&AsH[off];
                al[i] = *(const short8*)&AsL[off];
            }
            #pragma unroll
            for (int j = 0; j < 2; ++j) {
                const int off = (wn * 64 + j * 32 + lr) * 20 + c * 8 + g * 4;
                bh[j] = *(const short8*)&WsH[off];
                bl[j] = *(const short8*)&WsL[off];
            }
            #pragma unroll
            for (int i = 0; i < 2; ++i)
                #pragma unroll
                for (int j = 0; j < 2; ++j) {
                    acc[i][j] = __builtin_amdgcn_mfma_f32_32x32x16_bf16(ah[i], bh[j], acc[i][j], 0, 0, 0);
                    acc[i][j] = __builtin_amdgcn_mfma_f32_32x32x16_bf16(ah[i], bl[j], acc[i][j], 0, 0, 0);
                    acc[i][j] = __builtin_amdgcn_mfma_f32_32x32x16_bf16(al[i], bh[j], acc[i][j], 0, 0, 0);
                }
        }
    }

    // epilogue: D row = (r&3) + 8*(r>>2) + 4*g  (m101-verified), col = lane&31
    #pragma unroll
    for (int i = 0; i < 2; ++i)
        #pragma unroll
        for (int j = 0; j < 2; ++j) {
            const int col = n0 + wn * 64 + j * 32 + lr;
            const float bv = bias[col];
            #pragma unroll
            for (int r = 0; r < 16; ++r) {
                const int row = m0 + wm * 64 + i * 32 + (r & 3) + ((r >> 2) << 3) + (g << 2);
                const float v = acc[i][j][r] + bv;
                if (MODE == 0) {
                    const int bb = row >> 11, n = row & 2047;
                    const int hh = col >> 6,  dk = col & 63;
                    Out[(((size_t)(bb * HH + hh)) * NN + n) * DKK + dk] = v;
                } else {
                    Out[(size_t)row * DD + col] = v;
                }
            }
        }
}

// ---------------------------------------------------------------------------
// Split-bf16 MFMA flash attention. Block = 4 waves x 32 q-rows = 128 q-rows
// of one (b,h). Swapped QK^T: S^T = mfma(K, Q^T) -> lane's column q = lane&31,
// 16 regs = 16 of 32 keys (partner half in lane^32). Softmax in-register.
// PV computes O^T = mfma(V^T, P^T): rescale/divide are per-lane scalars.
// P -> B-frags via pure-register group swap (shfl_xor 32), no LDS.
// exp2-domain: Q pre-scaled by 0.125*log2(e).
// ---------------------------------------------------------------------------
__global__ __launch_bounds__(256) void attn_mfma(const float* __restrict__ Qw,
                                                 const float* __restrict__ Kw,
                                                 const float* __restrict__ Vw,
                                                 float* __restrict__ Ctx)
{
    __shared__ u32 KH[32 * 36], KL[32 * 36];   // K [key][dk], stride 72 ushort
    __shared__ u32 VH[64 * 20], VL[64 * 20];   // V^T [dk][key], stride 40 ushort

    const int tid  = threadIdx.x;
    const int lane = tid & 63;
    const int wid  = tid >> 6;
    const int g    = lane >> 5;
    const int lq   = lane & 31;
    const int bh = blockIdx.y, b = bh >> 3, h = bh & 7;
    const int q  = blockIdx.x * 128 + wid * 32 + lq;

    const float SC = 0.125f * 1.44269504f;   // 1/sqrt(64) * log2(e)

    // Q fragments in registers: B-operand of QK^T. 4 chunks of K=16.
    short8 qh[4], ql[4];
    {
        const float* qp = &Qw[((size_t)bh * NN + q) * DKK];
        #pragma unroll
        for (int c = 0; c < 4; ++c) {
            const int d0 = c * 16 + g * 8;
            float4 x0 = *(const float4*)&qp[d0];
            float4 x1 = *(const float4*)&qp[d0 + 4];
            float f[8] = {x0.x, x0.y, x0.z, x0.w, x1.x, x1.y, x1.z, x1.w};
            union { u32 u[4]; short8 v; } Hf, Lf;
            #pragma unroll
            for (int j = 0; j < 4; ++j)
                split_pk(f[2*j] * SC, f[2*j+1] * SC, Hf.u[j], Lf.u[j]);
            qh[c] = Hf.v; ql[c] = Lf.v;
        }
    }

    f32x16 acco[2];
    #pragma unroll
    for (int mf = 0; mf < 2; ++mf)
        #pragma unroll
        for (int r = 0; r < 16; ++r) acco[mf][r] = 0.f;
    float m_run = -1e30f, l_run = 0.f;

    const int skey = tid >> 3,  sdc = (tid & 7) * 8;   // K staging map
    const int vdk  = tid & 63,  vkg = (tid >> 6) * 8;  // V^T staging map

    for (int kt = 0; kt < NN; kt += 32) {
        __syncthreads();
        {   // stage K tile 32x64 natural (hi/lo)
            const float* kp = &Kw[((size_t)bh * NN + kt + skey) * DKK + sdc];
            float4 x0 = *(const float4*)&kp[0];
            float4 x1 = *(const float4*)&kp[4];
            float f[8] = {x0.x, x0.y, x0.z, x0.w, x1.x, x1.y, x1.z, x1.w};
            u32 hw[4], lw[4];
            #pragma unroll
            for (int j = 0; j < 4; ++j) split_pk(f[2*j], f[2*j+1], hw[j], lw[j]);
            const int base = skey * 36 + sdc / 2;
            *(uint4*)&KH[base] = *(uint4*)&hw[0];
            *(uint4*)&KL[base] = *(uint4*)&lw[0];
        }
        {   // stage V^T tile [dk][key] (hi/lo)
            const float* vp = &Vw[((size_t)bh * NN + kt) * DKK + vdk];
            float f[8];
            #pragma unroll
            for (int j = 0; j < 8; ++j) f[j] = vp[(size_t)(vkg + j) * DKK];
            u32 hw[4], lw[4];
            #pragma unroll
            for (int j = 0; j < 4; ++j) split_pk(f[2*j], f[2*j+1], hw[j], lw[j]);
            const int base = vdk * 20 + vkg / 2;
            *(uint4*)&VH[base] = *(uint4*)&hw[0];
            *(uint4*)&VL[base] = *(uint4*)&lw[0];
        }
        __syncthreads();

        // S^T = K @ Q^T  (A = K-tile, B = Q^T), 4 chunks x 3 split terms
        f32x16 s;
        #pragma unroll
        for (int r = 0; r < 16; ++r) s[r] = 0.f;
        #pragma unroll
        for (int c = 0; c < 4; ++c) {
            const int off = lq * 36 + c * 8 + g * 4;
            short8 kh = *(const short8*)&KH[off];
            short8 kl = *(const short8*)&KL[off];
            s = __builtin_amdgcn_mfma_f32_32x32x16_bf16(kh, qh[c], s, 0, 0, 0);
            s = __builtin_amdgcn_mfma_f32_32x32x16_bf16(kh, ql[c], s, 0, 0, 0);
            s = __builtin_amdgcn_mfma_f32_32x32x16_bf16(kl, qh[c], s, 0, 0, 0);
        }

        // online softmax over this tile's 32 keys (16 in-lane + 16 in lane^32)
        float mt = s[0];
        #pragma unroll
        for (int r = 1; r < 16; ++r) mt = fmaxf(mt, s[r]);
        mt = fmaxf(mt, __shfl_xor(mt, 32));
        const float mn = fmaxf(m_run, mt);
        const float alpha = exp2f(m_run - mn);
        float p[16], ls = 0.f;
        #pragma unroll
        for (int r = 0; r < 16; ++r) { p[r] = exp2f(s[r] - mn); ls += p[r]; }
        ls += __shfl_xor(ls, 32);
        l_run = l_run * alpha + ls;
        m_run = mn;
        #pragma unroll
        for (int mf = 0; mf < 2; ++mf)
            #pragma unroll
            for (int r = 0; r < 16; ++r) acco[mf][r] *= alpha;

        // split P into bf16 hi/lo packed words; group gg = regs 4gg..4gg+3
        u32 wH[8], wL[8], xH[8], xL[8];
        #pragma unroll
        for (int j = 0; j < 8; ++j) split_pk(p[2*j], p[2*j+1], wH[j], wL[j]);
        #pragma unroll
        for (int j = 0; j < 8; ++j) {
            xH[j] = __shfl_xor(wH[j], 32);
            xL[j] = __shfl_xor(wL[j], 32);
        }
        // assemble P^T B-frags: chunk c keys 16c..16c+15
        // own keys = crow(reg,g); partner supplies the complementary 4-group
        short8 pfH[2], pfL[2];
        #pragma unroll
        for (int c = 0; c < 2; ++c) {
            const int g0 = 2 * c + g;
            union { u32 u[4]; short8 v; } FH, FL;
            FH.u[0] = g ? xH[2*g0]   : wH[2*g0];
            FH.u[1] = g ? xH[2*g0+1] : wH[2*g0+1];
            FH.u[2] = g ? wH[2*g0]   : xH[2*g0];
            FH.u[3] = g ? wH[2*g0+1] : xH[2*g0+1];
            FL.u[0] = g ? xL[2*g0]   : wL[2*g0];
            FL.u[1] = g ? xL[2*g0+1] : wL[2*g0+1];
            FL.u[2] = g ? wL[2*g0]   : xL[2*g0];
            FL.u[3] = g ? wL[2*g0+1] : xL[2*g0+1];
            pfH[c] = FH.v; pfL[c] = FL.v;
        }

        // O^T += V^T @ P^T   (A = V^T, B = P^T)
        #pragma unroll
        for (int mf = 0; mf < 2; ++mf)
            #pragma unroll
            for (int c = 0; c < 2; ++c) {
                const int off = (mf * 32 + lq) * 20 + c * 8 + g * 4;
                short8 vh = *(const short8*)&VH[off];
                short8 vl = *(const short8*)&VL[off];
                acco[mf] = __builtin_amdgcn_mfma_f32_32x32x16_bf16(vh, pfH[c], acco[mf], 0, 0, 0);
                acco[mf] = __builtin_amdgcn_mfma_f32_32x32x16_bf16(vh, pfL[c], acco[mf], 0, 0, 0);
                acco[mf] = __builtin_amdgcn_mfma_f32_32x32x16_bf16(vl, pfH[c], acco[mf], 0, 0, 0);
            }
    }

    // write ctx: O^T rows = dk = (r&3)+8*(r>>2)+4g (+32*mf), col = q = lane&31
    const float inv = 1.f / l_run;
    const size_t rowbase = ((size_t)b * NN + q) * DD + h * DKK;
    #pragma unroll
    for (int mf = 0; mf < 2; ++mf)
        #pragma unroll
        for (int qd = 0; qd < 4; ++qd) {
            const int dk = mf * 32 + 8 * qd + 4 * g;
            float4 v = make_float4(acco[mf][4*qd] * inv, acco[mf][4*qd+1] * inv,
                                   acco[mf][4*qd+2] * inv, acco[mf][4*qd+3] * inv);
            *(float4*)&Ctx[rowbase + dk] = v;
        }
}

// ---------------------------------------------------------------------------
extern "C" void kernel_launch(void* const* d_in, const int* in_sizes, int n_in,
                              void* d_out, int out_size, void* d_ws, size_t ws_size,
                              hipStream_t stream) {
    const float* q  = (const float*)d_in[0];
    const float* k  = (const float*)d_in[1];
    const float* v  = (const float*)d_in[2];
    const float* Wq = (const float*)d_in[3];
    const float* bq = (const float*)d_in[4];
    const float* Wk = (const float*)d_in[5];
    const float* bk = (const float*)d_in[6];
    const float* Wv = (const float*)d_in[7];
    const float* bv = (const float*)d_in[8];
    const float* Wo = (const float*)d_in[9];
    const float* bo = (const float*)d_in[10];

    float* ws = (float*)d_ws;
    const size_t PER = (size_t)BB * NN * DD;   // 4,194,304 floats per tensor
    float* Qw  = ws;
    float* Kw  = ws + PER;
    float* Vw  = ws + 2 * PER;
    float* Ctx = ws + 3 * PER;                 // 64 MB total workspace

    dim3 blk(256);
    // fused Q/K/V projections (z selects input/weight), head-split output
    gemm_mfma<0><<<dim3(64, 4, 3), blk, 0, stream>>>(q, k, v, Wq, Wk, Wv, bq, bk, bv, ws);
    // flash attention
    attn_mfma<<<dim3(16, 32), blk, 0, stream>>>(Qw, Kw, Vw, Ctx);
    // output projection
    gemm_mfma<1><<<dim3(64, 4, 1), blk, 0, stream>>>(Ctx, Ctx, Ctx, Wo, Wo, Wo,
                                                     bo, bo, bo, (float*)d_out);
}

// Round 7
// 466.102 us; speedup vs baseline: 1.0898x; 1.0898x over previous
//
#include <hip/hip_runtime.h>
#include <hip/hip_bf16.h>

#define BB 4
#define NN 2048
#define DD 512
#define HH 8
#define DKK 64

typedef unsigned int u32;
typedef __attribute__((ext_vector_type(8))) short short8;    // 8 bf16 = 4 VGPRs
typedef __attribute__((ext_vector_type(16))) float f32x16;   // mfma 32x32 acc

// ---- bf16 split helpers (hi = rne(x), lo = rne(x - hi)) --------------------
__device__ __forceinline__ u32 pk_bf2(float a, float b) {
    union { __hip_bfloat162 h; u32 u; } cv;
    cv.h = __float22bfloat162_rn(make_float2(a, b));
    return cv.u;
}
__device__ __forceinline__ float2 upk_bf2(u32 w) {
    union { u32 u; __hip_bfloat162 h; } cv;
    cv.u = w;
    return __bfloat1622float2(cv.h);
}
__device__ __forceinline__ void split_pk(float a, float b, u32& hw, u32& lw) {
    hw = pk_bf2(a, b);
    float2 hf = upk_bf2(hw);
    lw = pk_bf2(a - hf.x, b - hf.y);
}

// ---------------------------------------------------------------------------
// Weight pre-split: W[512][512] (row = k, col = n) -> transposed packed
// hi/lo bf16: WT[n][k/2] as u32 (bf16 pair, k even in low half).
// blockIdx.y selects tensor {Wq,Wk,Wv,Wo}; output offset t*131072 u32.
// ---------------------------------------------------------------------------
__global__ __launch_bounds__(256) void wsplit(const float* __restrict__ W0,
                                              const float* __restrict__ W1,
                                              const float* __restrict__ W2,
                                              const float* __restrict__ W3,
                                              u32* __restrict__ WTH,
                                              u32* __restrict__ WTL) {
    const int idx = blockIdx.x * 256 + threadIdx.x;   // 0..32767
    const int n  = idx & 511;
    const int kg = idx >> 9;                           // 0..63 (8 k each)
    const int t  = blockIdx.y;
    const float* W = (t == 0) ? W0 : (t == 1) ? W1 : (t == 2) ? W2 : W3;
    float f[8];
    #pragma unroll
    for (int j = 0; j < 8; ++j) f[j] = W[(size_t)(kg * 8 + j) * 512 + n];
    u32 hw[4], lw[4];
    #pragma unroll
    for (int j = 0; j < 4; ++j) split_pk(f[2*j], f[2*j+1], hw[j], lw[j]);
    const size_t ob = (size_t)t * 131072 + (size_t)n * 256 + kg * 4;
    *(uint4*)&WTH[ob] = *(uint4*)&hw[0];
    *(uint4*)&WTL[ob] = *(uint4*)&lw[0];
}

// ---------------------------------------------------------------------------
// Split-bf16 MFMA GEMM: C[M,512] = A[M,512] @ W[512,512] + bias
// 128x128 tile, BK=32, 4 waves (2x2), per-wave 64x64 = 2x2 frags of 32x32.
// W side reads pre-split/pre-transposed hi/lo bf16 (wsplit) — W staging
// is a pure uint4 copy. A side / MFMA loop / epilogue UNCHANGED from round 3.
// ---------------------------------------------------------------------------
template<int MODE>
__global__ __launch_bounds__(256) void gemm_mfma(
    const float* __restrict__ A0, const float* __restrict__ A1, const float* __restrict__ A2,
    const u32* __restrict__ WTH_base, const u32* __restrict__ WTL_base,
    const float* __restrict__ B0, const float* __restrict__ B1, const float* __restrict__ B2,
    float* __restrict__ OutBase)
{
    __shared__ u32 AsH[128 * 20], AsL[128 * 20], WsH[128 * 20], WsL[128 * 20];

    const int tid  = threadIdx.x;
    const int lane = tid & 63;
    const int wid  = tid >> 6;
    const int g    = lane >> 5;
    const int lr   = lane & 31;
    const int wm   = wid >> 1, wn = wid & 1;
    const int m0 = blockIdx.x * 128, n0 = blockIdx.y * 128;
    const int z  = blockIdx.z;

    const float* A    = (z == 0) ? A0 : (z == 1) ? A1 : A2;
    const float* bias = (z == 0) ? B0 : (z == 1) ? B1 : B2;
    const u32* WTH = WTH_base + (size_t)z * 131072;
    const u32* WTL = WTL_base + (size_t)z * 131072;
    float* Out = (MODE == 0) ? (OutBase + (size_t)z * ((size_t)BB * NN * DD)) : OutBase;

    f32x16 acc[2][2];
    #pragma unroll
    for (int i = 0; i < 2; ++i)
        #pragma unroll
        for (int j = 0; j < 2; ++j)
            #pragma unroll
            for (int r = 0; r < 16; ++r) acc[i][j][r] = 0.f;

    const int arow = tid >> 1, akc = (tid & 1) * 16;     // A staging map
    const int wrow = tid >> 1, wkk = (tid & 1) * 8;      // W staging map (u32)

    for (int k0 = 0; k0 < DD; k0 += 32) {
        __syncthreads();
        {   // stage A tile 128x32 (fp32 -> hi/lo bf16), layout [row][kk] stride 20
            const float* ap = &A[(size_t)(m0 + arow) * DD + k0 + akc];
            float f[16];
            *(float4*)&f[0]  = *(const float4*)&ap[0];
            *(float4*)&f[4]  = *(const float4*)&ap[4];
            *(float4*)&f[8]  = *(const float4*)&ap[8];
            *(float4*)&f[12] = *(const float4*)&ap[12];
            u32 hw[8], lw[8];
            #pragma unroll
            for (int j = 0; j < 8; ++j) split_pk(f[2*j], f[2*j+1], hw[j], lw[j]);
            const int base = arow * 20 + akc / 2;
            *(uint4*)&AsH[base]     = *(uint4*)&hw[0];
            *(uint4*)&AsH[base + 4] = *(uint4*)&hw[4];
            *(uint4*)&AsL[base]     = *(uint4*)&lw[0];
            *(uint4*)&AsL[base + 4] = *(uint4*)&lw[4];
        }
        {   // stage W tile 128 cols x 16 kk from pre-split: pure uint4 copy
            const size_t gb = (size_t)(n0 + wrow) * 256 + (k0 >> 1) + wkk;
            const int lb = wrow * 20 + wkk;
            *(uint4*)&WsH[lb]     = *(const uint4*)&WTH[gb];
            *(uint4*)&WsH[lb + 4] = *(const uint4*)&WTH[gb + 4];
            *(uint4*)&WsL[lb]     = *(const uint4*)&WTL[gb];
            *(uint4*)&WsL[lb + 4] = *(const uint4*)&WTL[gb + 4];
        }
        __syncthreads();

        #pragma unroll
        for (int c = 0; c < 2; ++c) {
            short8 ah[2], al[2], bh[2], bl[2];
            #pragma unroll
            for (int i = 0; i < 2; ++i) {
                const int off = (wm * 64 + i * 32 + lr) * 20 + c * 8 + g * 4;
                ah[i] = *(const short8*)&AsH[off];
                al[i] = *(const short8*)&AsL[off];
            }
            #pragma unroll
            for (int j = 0; j < 2; ++j) {
                const int off = (wn * 64 + j * 32 + lr) * 20 + c * 8 + g * 4;
                bh[j] = *(const short8*)&WsH[off];
                bl[j] = *(const short8*)&WsL[off];
            }
            #pragma unroll
            for (int i = 0; i < 2; ++i)
                #pragma unroll
                for (int j = 0; j < 2; ++j) {
                    acc[i][j] = __builtin_amdgcn_mfma_f32_32x32x16_bf16(ah[i], bh[j], acc[i][j], 0, 0, 0);
                    acc[i][j] = __builtin_amdgcn_mfma_f32_32x32x16_bf16(ah[i], bl[j], acc[i][j], 0, 0, 0);
                    acc[i][j] = __builtin_amdgcn_mfma_f32_32x32x16_bf16(al[i], bh[j], acc[i][j], 0, 0, 0);
                }
        }
    }

    // epilogue: D row = (r&3) + 8*(r>>2) + 4*g (m101-verified), col = lane&31
    #pragma unroll
    for (int i = 0; i < 2; ++i)
        #pragma unroll
        for (int j = 0; j < 2; ++j) {
            const int col = n0 + wn * 64 + j * 32 + lr;
            const float bv = bias[col];
            #pragma unroll
            for (int r = 0; r < 16; ++r) {
                const int row = m0 + wm * 64 + i * 32 + (r & 3) + ((r >> 2) << 3) + (g << 2);
                const float v = acc[i][j][r] + bv;
                if (MODE == 0) {
                    const int bb = row >> 11, n = row & 2047;
                    const int hh = col >> 6,  dk = col & 63;
                    Out[(((size_t)(bb * HH + hh)) * NN + n) * DKK + dk] = v;
                } else {
                    Out[(size_t)row * DD + col] = v;
                }
            }
        }
}

// ---------------------------------------------------------------------------
// Split-bf16 MFMA flash attention v2.  (BYTE-IDENTICAL to round 4)
// Block = 8 waves (512 thr). Waves 0-3 process KV[0:1024), waves 4-7 process
// KV[1024:2048) for the SAME 128 q-rows; private staging; LDS (m,l,acc) merge.
// __launch_bounds__(512,4) caps regs at 128 (round-3 chose 80 and spilled).
// ---------------------------------------------------------------------------
__global__ __launch_bounds__(512, 4) void attn_mfma(const float* __restrict__ Qw,
                                                    const float* __restrict__ Kw,
                                                    const float* __restrict__ Vw,
                                                    float* __restrict__ Ctx)
{
    // u32 layout: per group (grp*4864): KH[32*36] KL[32*36] VH[64*20] VL[64*20]
    // combine overlay (after loop): C float[4][64][33] @0, ml float[4][32][2] @8448
    __shared__ u32 lds[9728];

    const int tid  = threadIdx.x;
    const int lane = tid & 63;
    const int wid  = tid >> 6;       // 0..7
    const int grp  = wid >> 2;       // KV half
    const int qw   = wid & 3;        // q-wave within group
    const int g    = lane >> 5;
    const int lq   = lane & 31;
    const int bh = blockIdx.y, b = bh >> 3, h = bh & 7;
    const int q  = blockIdx.x * 128 + qw * 32 + lq;

    u32* const KH = lds + grp * 4864;
    u32* const KL = KH + 1152;
    u32* const VH = KH + 2304;
    u32* const VL = KH + 3584;

    const float SC = 0.125f * 1.44269504f;   // 1/sqrt(64) * log2(e)

    // Q fragments in registers (B-operand of QK^T), 4 chunks of K=16
    short8 qh[4], ql[4];
    {
        const float* qp = &Qw[((size_t)bh * NN + q) * DKK];
        #pragma unroll
        for (int c = 0; c < 4; ++c) {
            const int d0 = c * 16 + g * 8;
            float4 x0 = *(const float4*)&qp[d0];
            float4 x1 = *(const float4*)&qp[d0 + 4];
            float f[8] = {x0.x, x0.y, x0.z, x0.w, x1.x, x1.y, x1.z, x1.w};
            union { u32 u[4]; short8 v; } Hf, Lf;
            #pragma unroll
            for (int j = 0; j < 4; ++j)
                split_pk(f[2*j] * SC, f[2*j+1] * SC, Hf.u[j], Lf.u[j]);
            qh[c] = Hf.v; ql[c] = Lf.v;
        }
    }

    f32x16 acco[2];
    #pragma unroll
    for (int mf = 0; mf < 2; ++mf)
        #pragma unroll
        for (int r = 0; r < 16; ++r) acco[mf][r] = 0.f;
    float m_run = -1e30f, l_run = 0.f;

    // staging maps within the group's 256 threads
    const int gt   = tid & 255;
    const int skey = gt >> 3,  sdc = (gt & 7) * 8;
    const int vdk  = gt & 63,  vkg = (gt >> 6) * 8;
    const size_t kvrow = (size_t)bh * NN;
    const int kv0 = grp * 1024;

    for (int t = 0; t < 32; ++t) {
        const int kt = kv0 + t * 32;
        __syncthreads();
        {   // stage K tile 32x64 (hi/lo), rows = key, stride 36 u32
            const float* kp = &Kw[(kvrow + kt + skey) * DKK + sdc];
            float4 x0 = *(const float4*)&kp[0];
            float4 x1 = *(const float4*)&kp[4];
            float f[8] = {x0.x, x0.y, x0.z, x0.w, x1.x, x1.y, x1.z, x1.w};
            u32 hw[4], lw[4];
            #pragma unroll
            for (int j = 0; j < 4; ++j) split_pk(f[2*j], f[2*j+1], hw[j], lw[j]);
            const int base = skey * 36 + sdc / 2;
            *(uint4*)&KH[base] = *(uint4*)&hw[0];
            *(uint4*)&KL[base] = *(uint4*)&lw[0];
        }
        {   // stage V^T tile [dk][key] (hi/lo), stride 20 u32
            const float* vp = &Vw[(kvrow + kt) * DKK + vdk];
            float f[8];
            #pragma unroll
            for (int j = 0; j < 8; ++j) f[j] = vp[(size_t)(vkg + j) * DKK];
            u32 hw[4], lw[4];
            #pragma unroll
            for (int j = 0; j < 4; ++j) split_pk(f[2*j], f[2*j+1], hw[j], lw[j]);
            const int base = vdk * 20 + vkg / 2;
            *(uint4*)&VH[base] = *(uint4*)&hw[0];
            *(uint4*)&VL[base] = *(uint4*)&lw[0];
        }
        __syncthreads();

        // S^T = K @ Q^T, 4 chunks x 3 split terms
        f32x16 s;
        #pragma unroll
        for (int r = 0; r < 16; ++r) s[r] = 0.f;
        #pragma unroll
        for (int c = 0; c < 4; ++c) {
            const int off = lq * 36 + c * 8 + g * 4;
            short8 kh = *(const short8*)&KH[off];
            short8 kl = *(const short8*)&KL[off];
            s = __builtin_amdgcn_mfma_f32_32x32x16_bf16(kh, qh[c], s, 0, 0, 0);
            s = __builtin_amdgcn_mfma_f32_32x32x16_bf16(kh, ql[c], s, 0, 0, 0);
            s = __builtin_amdgcn_mfma_f32_32x32x16_bf16(kl, qh[c], s, 0, 0, 0);
        }

        // online softmax over this tile's 32 keys
        float mt = s[0];
        #pragma unroll
        for (int r = 1; r < 16; ++r) mt = fmaxf(mt, s[r]);
        mt = fmaxf(mt, __shfl_xor(mt, 32));
        const float mn = fmaxf(m_run, mt);
        const float alpha = exp2f(m_run - mn);
        float p[16], ls = 0.f;
        #pragma unroll
        for (int r = 0; r < 16; ++r) { p[r] = exp2f(s[r] - mn); ls += p[r]; }
        ls += __shfl_xor(ls, 32);
        l_run = l_run * alpha + ls;
        m_run = mn;
        #pragma unroll
        for (int mf = 0; mf < 2; ++mf)
            #pragma unroll
            for (int r = 0; r < 16; ++r) acco[mf][r] *= alpha;

        // split P -> packed bf16 hi/lo words
        u32 wH[8], wL[8];
        #pragma unroll
        for (int j = 0; j < 8; ++j) split_pk(p[2*j], p[2*j+1], wH[j], wL[j]);

        // ---- hi pass: exchange wH, build pfH, apply (vh*pH + vl*pH) ----
        {
            u32 xH[8];
            #pragma unroll
            for (int j = 0; j < 8; ++j) xH[j] = __shfl_xor(wH[j], 32);
            short8 pfH[2];
            #pragma unroll
            for (int c = 0; c < 2; ++c) {
                const int g0 = 2 * c + g;
                union { u32 u[4]; short8 v; } FH;
                FH.u[0] = g ? xH[2*g0]   : wH[2*g0];
                FH.u[1] = g ? xH[2*g0+1] : wH[2*g0+1];
                FH.u[2] = g ? wH[2*g0]   : xH[2*g0];
                FH.u[3] = g ? wH[2*g0+1] : xH[2*g0+1];
                pfH[c] = FH.v;
            }
            #pragma unroll
            for (int mf = 0; mf < 2; ++mf)
                #pragma unroll
                for (int c = 0; c < 2; ++c) {
                    const int off = (mf * 32 + lq) * 20 + c * 8 + g * 4;
                    short8 vh = *(const short8*)&VH[off];
                    short8 vl = *(const short8*)&VL[off];
                    acco[mf] = __builtin_amdgcn_mfma_f32_32x32x16_bf16(vh, pfH[c], acco[mf], 0, 0, 0);
                    acco[mf] = __builtin_amdgcn_mfma_f32_32x32x16_bf16(vl, pfH[c], acco[mf], 0, 0, 0);
                }
        }
        // ---- lo pass: exchange wL, build pfL, apply (vh*pL) ----
        {
            u32 xL[8];
            #pragma unroll
            for (int j = 0; j < 8; ++j) xL[j] = __shfl_xor(wL[j], 32);
            short8 pfL[2];
            #pragma unroll
            for (int c = 0; c < 2; ++c) {
                const int g0 = 2 * c + g;
                union { u32 u[4]; short8 v; } FL;
                FL.u[0] = g ? xL[2*g0]   : wL[2*g0];
                FL.u[1] = g ? xL[2*g0+1] : wL[2*g0+1];
                FL.u[2] = g ? wL[2*g0]   : xL[2*g0];
                FL.u[3] = g ? wL[2*g0+1] : xL[2*g0+1];
                pfL[c] = FL.v;
            }
            #pragma unroll
            for (int mf = 0; mf < 2; ++mf)
                #pragma unroll
                for (int c = 0; c < 2; ++c) {
                    const int off = (mf * 32 + lq) * 20 + c * 8 + g * 4;
                    short8 vh = *(const short8*)&VH[off];
                    acco[mf] = __builtin_amdgcn_mfma_f32_32x32x16_bf16(vh, pfL[c], acco[mf], 0, 0, 0);
                }
        }
    }

    // ---- combine the two KV halves via LDS ----
    __syncthreads();                        // all staging use done
    float* C  = (float*)lds;                // [4][64][33]
    float* ml = (float*)(lds + 8448);       // [4][32][2]
    if (grp == 1) {
        #pragma unroll
        for (int mf = 0; mf < 2; ++mf)
            #pragma unroll
            for (int qd = 0; qd < 4; ++qd) {
                const int dkb = mf * 32 + 8 * qd + 4 * g;
                #pragma unroll
                for (int e = 0; e < 4; ++e)
                    C[qw * 2112 + (dkb + e) * 33 + lq] = acco[mf][4*qd + e];
            }
        if (g == 0) {
            ml[qw * 64 + lq * 2]     = m_run;
            ml[qw * 64 + lq * 2 + 1] = l_run;
        }
    }
    __syncthreads();
    if (grp == 0) {
        const float m1 = ml[qw * 64 + lq * 2];
        const float l1 = ml[qw * 64 + lq * 2 + 1];
        const float mN = fmaxf(m_run, m1);
        const float a0 = exp2f(m_run - mN);
        const float a1 = exp2f(m1 - mN);
        const float inv = 1.f / (a0 * l_run + a1 * l1);
        const size_t rowbase = ((size_t)b * NN + q) * DD + h * DKK;
        #pragma unroll
        for (int mf = 0; mf < 2; ++mf)
            #pragma unroll
            for (int qd = 0; qd < 4; ++qd) {
                const int dkb = mf * 32 + 8 * qd + 4 * g;
                float4 v;
                v.x = (a0 * acco[mf][4*qd+0] + a1 * C[qw * 2112 + (dkb+0) * 33 + lq]) * inv;
                v.y = (a0 * acco[mf][4*qd+1] + a1 * C[qw * 2112 + (dkb+1) * 33 + lq]) * inv;
                v.z = (a0 * acco[mf][4*qd+2] + a1 * C[qw * 2112 + (dkb+2) * 33 + lq]) * inv;
                v.w = (a0 * acco[mf][4*qd+3] + a1 * C[qw * 2112 + (dkb+3) * 33 + lq]) * inv;
                *(float4*)&Ctx[rowbase + dkb] = v;
            }
    }
}

// ---------------------------------------------------------------------------
extern "C" void kernel_launch(void* const* d_in, const int* in_sizes, int n_in,
                              void* d_out, int out_size, void* d_ws, size_t ws_size,
                              hipStream_t stream) {
    const float* q  = (const float*)d_in[0];
    const float* k  = (const float*)d_in[1];
    const float* v  = (const float*)d_in[2];
    const float* Wq = (const float*)d_in[3];
    const float* bq = (const float*)d_in[4];
    const float* Wk = (const float*)d_in[5];
    const float* bk = (const float*)d_in[6];
    const float* Wv = (const float*)d_in[7];
    const float* bv = (const float*)d_in[8];
    const float* Wo = (const float*)d_in[9];
    const float* bo = (const float*)d_in[10];

    float* ws = (float*)d_ws;
    const size_t PER = (size_t)BB * NN * DD;   // 4,194,304 floats per tensor
    float* Qw  = ws;
    float* Kw  = ws + PER;
    float* Vw  = ws + 2 * PER;
    float* Ctx = ws + 3 * PER;
    u32*   WTH = (u32*)(ws + 4 * PER);         // 4 x 131072 u32 (2 MB)
    u32*   WTL = WTH + 4 * 131072;             // 4 x 131072 u32 (2 MB)
                                               // total ws: ~71.3 MB

    // weight pre-split/transpose (all 4 weight matrices)
    wsplit<<<dim3(128, 4), dim3(256), 0, stream>>>(Wq, Wk, Wv, Wo, WTH, WTL);
    // fused Q/K/V projections (z selects input/weight), head-split output
    gemm_mfma<0><<<dim3(64, 4, 3), dim3(256), 0, stream>>>(q, k, v, WTH, WTL,
                                                           bq, bk, bv, ws);
    // flash attention (8-wave blocks, intra-block KV split)
    attn_mfma<<<dim3(16, 32), dim3(512), 0, stream>>>(Qw, Kw, Vw, Ctx);
    // output projection
    gemm_mfma<1><<<dim3(64, 4, 1), dim3(256), 0, stream>>>(Ctx, Ctx, Ctx,
                                                           WTH + 3 * 131072, WTL + 3 * 131072,
                                                           bo, bo, bo, (float*)d_out);
}

// Round 8
// 366.886 us; speedup vs baseline: 1.3845x; 1.2704x over previous
//
#include <hip/hip_runtime.h>
#include <hip/hip_bf16.h>

#define BB 4
#define NN 2048
#define DD 512
#define HH 8
#define DKK 64

typedef unsigned int u32;
typedef unsigned short u16;
typedef __attribute__((ext_vector_type(8))) short short8;    // 8 bf16 = 4 VGPRs
typedef __attribute__((ext_vector_type(16))) float f32x16;   // mfma 32x32 acc

// ---- bf16 split helpers (hi = rne(x), lo = rne(x - hi)) --------------------
__device__ __forceinline__ u32 pk_bf2(float a, float b) {
    union { __hip_bfloat162 h; u32 u; } cv;
    cv.h = __float22bfloat162_rn(make_float2(a, b));
    return cv.u;
}
__device__ __forceinline__ float2 upk_bf2(u32 w) {
    union { u32 u; __hip_bfloat162 h; } cv;
    cv.u = w;
    return __bfloat1622float2(cv.h);
}
__device__ __forceinline__ void split_pk(float a, float b, u32& hw, u32& lw) {
    hw = pk_bf2(a, b);
    float2 hf = upk_bf2(hw);
    lw = pk_bf2(a - hf.x, b - hf.y);
}
__device__ __forceinline__ void split16(float v, u16& h, u16& l) {
    u32 hw = pk_bf2(v, v);
    float hf = upk_bf2(hw).x;
    u32 lw = pk_bf2(v - hf, v - hf);
    h = (u16)(hw & 0xffffu);
    l = (u16)(lw & 0xffffu);
}

// ---------------------------------------------------------------------------
// Weight pre-split: W[512][512] (row=k,col=n) -> WT[n][k/2] u32 (bf16 pair).
// ---------------------------------------------------------------------------
__global__ __launch_bounds__(256) void wsplit(const float* __restrict__ W0,
                                              const float* __restrict__ W1,
                                              const float* __restrict__ W2,
                                              const float* __restrict__ W3,
                                              u32* __restrict__ WTH,
                                              u32* __restrict__ WTL) {
    const int idx = blockIdx.x * 256 + threadIdx.x;   // 0..32767
    const int n  = idx & 511;
    const int kg = idx >> 9;                           // 0..63
    const int t  = blockIdx.y;
    const float* W = (t == 0) ? W0 : (t == 1) ? W1 : (t == 2) ? W2 : W3;
    float f[8];
    #pragma unroll
    for (int j = 0; j < 8; ++j) f[j] = W[(size_t)(kg * 8 + j) * 512 + n];
    u32 hw[4], lw[4];
    #pragma unroll
    for (int j = 0; j < 4; ++j) split_pk(f[2*j], f[2*j+1], hw[j], lw[j]);
    const size_t ob = (size_t)t * 131072 + (size_t)n * 256 + kg * 4;
    *(uint4*)&WTH[ob] = *(uint4*)&hw[0];
    *(uint4*)&WTL[ob] = *(uint4*)&lw[0];
}

// ---------------------------------------------------------------------------
// Activation pre-split: x[8192][512] fp32 -> XH/XL [8192][256] u32 (pairs
// along k). Coalesced; each thread does 8 elements.
// ---------------------------------------------------------------------------
__global__ __launch_bounds__(256) void xsplit(const float* __restrict__ X,
                                              u32* __restrict__ XH,
                                              u32* __restrict__ XL) {
    const size_t i8 = (size_t)blockIdx.x * 256 + threadIdx.x;  // 0..524287
    const float* xp = &X[i8 * 8];
    float f[8];
    *(float4*)&f[0] = *(const float4*)&xp[0];
    *(float4*)&f[4] = *(const float4*)&xp[4];
    u32 hw[4], lw[4];
    #pragma unroll
    for (int j = 0; j < 4; ++j) split_pk(f[2*j], f[2*j+1], hw[j], lw[j]);
    *(uint4*)&XH[i8 * 4] = *(uint4*)&hw[0];
    *(uint4*)&XL[i8 * 4] = *(uint4*)&lw[0];
}

// ---------------------------------------------------------------------------
// Split-bf16 MFMA GEMM, both operands pre-split: staging = pure uint4 copies.
// 128x128 tile, BK=32, 4 waves (2x2), per-wave 64x64 = 2x2 frags of 32x32.
// MODE 0 (QKV), zsel selects output format:
//   zsel=0 -> Q head-split bf16 u16 [bh][n][64] (hi,lo) into O16H/O16L
//   zsel=1 -> K same layout into O16H/O16L
//   zsel=2 -> V transposed [bh][dk][n/2] u32 (pair along n) into VTH/VTL
// MODE 1 (out proj): fp32 OutF [m][512].
// ---------------------------------------------------------------------------
template<int MODE>
__global__ __launch_bounds__(256) void gemm_mfma(
    const u32* __restrict__ AH, const u32* __restrict__ AL,
    const u32* __restrict__ WTH, const u32* __restrict__ WTL,
    const float* __restrict__ bias,
    u16* __restrict__ O16H, u16* __restrict__ O16L,
    u32* __restrict__ VTH, u32* __restrict__ VTL,
    float* __restrict__ OutF, const int zsel)
{
    __shared__ u32 AsH[128 * 20], AsL[128 * 20], WsH[128 * 20], WsL[128 * 20];

    const int tid  = threadIdx.x;
    const int lane = tid & 63;
    const int wid  = tid >> 6;
    const int g    = lane >> 5;
    const int lr   = lane & 31;
    const int wm   = wid >> 1, wn = wid & 1;
    const int m0 = blockIdx.x * 128, n0 = blockIdx.y * 128;

    f32x16 acc[2][2];
    #pragma unroll
    for (int i = 0; i < 2; ++i)
        #pragma unroll
        for (int j = 0; j < 2; ++j)
            #pragma unroll
            for (int r = 0; r < 16; ++r) acc[i][j][r] = 0.f;

    const int row8 = tid >> 1;            // 0..127 (A row / W col)
    const int koff = (tid & 1) * 8;       // u32 offset within 16-u32 chunk

    for (int k0 = 0; k0 < DD; k0 += 32) {
        __syncthreads();
        {   // A tile: [row][k/2] u32
            const size_t gb = (size_t)(m0 + row8) * 256 + (k0 >> 1) + koff;
            const int lb = row8 * 20 + koff;
            *(uint4*)&AsH[lb]     = *(const uint4*)&AH[gb];
            *(uint4*)&AsH[lb + 4] = *(const uint4*)&AH[gb + 4];
            *(uint4*)&AsL[lb]     = *(const uint4*)&AL[gb];
            *(uint4*)&AsL[lb + 4] = *(const uint4*)&AL[gb + 4];
        }
        {   // W tile: [col][k/2] u32
            const size_t gb = (size_t)(n0 + row8) * 256 + (k0 >> 1) + koff;
            const int lb = row8 * 20 + koff;
            *(uint4*)&WsH[lb]     = *(const uint4*)&WTH[gb];
            *(uint4*)&WsH[lb + 4] = *(const uint4*)&WTH[gb + 4];
            *(uint4*)&WsL[lb]     = *(const uint4*)&WTL[gb];
            *(uint4*)&WsL[lb + 4] = *(const uint4*)&WTL[gb + 4];
        }
        __syncthreads();

        #pragma unroll
        for (int c = 0; c < 2; ++c) {
            short8 ah[2], al[2], bh[2], bl[2];
            #pragma unroll
            for (int i = 0; i < 2; ++i) {
                const int off = (wm * 64 + i * 32 + lr) * 20 + c * 8 + g * 4;
                ah[i] = *(const short8*)&AsH[off];
                al[i] = *(const short8*)&AsL[off];
            }
            #pragma unroll
            for (int j = 0; j < 2; ++j) {
                const int off = (wn * 64 + j * 32 + lr) * 20 + c * 8 + g * 4;
                bh[j] = *(const short8*)&WsH[off];
                bl[j] = *(const short8*)&WsL[off];
            }
            #pragma unroll
            for (int i = 0; i < 2; ++i)
                #pragma unroll
                for (int j = 0; j < 2; ++j) {
                    acc[i][j] = __builtin_amdgcn_mfma_f32_32x32x16_bf16(ah[i], bh[j], acc[i][j], 0, 0, 0);
                    acc[i][j] = __builtin_amdgcn_mfma_f32_32x32x16_bf16(ah[i], bl[j], acc[i][j], 0, 0, 0);
                    acc[i][j] = __builtin_amdgcn_mfma_f32_32x32x16_bf16(al[i], bh[j], acc[i][j], 0, 0, 0);
                }
        }
    }

    // epilogue: D row = (r&3) + 8*(r>>2) + 4*g (m101-verified), col = lane&31
    #pragma unroll
    for (int i = 0; i < 2; ++i)
        #pragma unroll
        for (int j = 0; j < 2; ++j) {
            const int col = n0 + wn * 64 + j * 32 + lr;   // 0..511
            const float bv = bias[col];
            if (MODE == 1) {
                #pragma unroll
                for (int r = 0; r < 16; ++r) {
                    const int row = m0 + wm * 64 + i * 32 + (r & 3) + ((r >> 2) << 3) + (g << 2);
                    OutF[(size_t)row * DD + col] = acc[i][j][r] + bv;
                }
            } else if (zsel == 2) {
                // V: transposed [bh][dk][n/2] u32, pairs along token n
                const int hh = col >> 6, dk = col & 63;
                #pragma unroll
                for (int r = 0; r < 16; r += 2) {
                    const int row = m0 + wm * 64 + i * 32 + (r & 3) + ((r >> 2) << 3) + (g << 2);
                    const int bb = row >> 11, n = row & 2047;
                    u32 hw, lw;
                    split_pk(acc[i][j][r] + bv, acc[i][j][r + 1] + bv, hw, lw);
                    const size_t vidx = ((size_t)(bb * HH + hh) * DKK + dk) * (NN / 2) + (n >> 1);
                    VTH[vidx] = hw;
                    VTL[vidx] = lw;
                }
            } else {
                // Q/K: head-split [bh][n][64] u16 hi/lo
                const int hh = col >> 6, dk = col & 63;
                #pragma unroll
                for (int r = 0; r < 16; ++r) {
                    const int row = m0 + wm * 64 + i * 32 + (r & 3) + ((r >> 2) << 3) + (g << 2);
                    const int bb = row >> 11, n = row & 2047;
                    u16 hb, lb2;
                    split16(acc[i][j][r] + bv, hb, lb2);
                    const size_t oidx = ((size_t)(bb * HH + hh) * NN + n) * DKK + dk;
                    O16H[oidx] = hb;
                    O16L[oidx] = lb2;
                }
            }
        }
}

// ---------------------------------------------------------------------------
// Split-bf16 MFMA flash attention v3 (see round-8 theory):
//  pre-split inputs (pure uint4 staging), raw-domain softmax w/ SC via fmaf,
//  STATIC exchange indices (v2's lane-varying reg indices forced scratch),
//  lazy wL, pre-split Ctx output.
// ---------------------------------------------------------------------------
__global__ __launch_bounds__(512, 4) void attn_mfma(
    const u16* __restrict__ QH16, const u16* __restrict__ QL16,
    const u16* __restrict__ KH16, const u16* __restrict__ KL16,
    const u32* __restrict__ VTH,  const u32* __restrict__ VTL,
    u32* __restrict__ CtxH, u32* __restrict__ CtxL)
{
    __shared__ u32 lds[9728];

    const int tid  = threadIdx.x;
    const int lane = tid & 63;
    const int wid  = tid >> 6;
    const int grp  = wid >> 2;
    const int qw   = wid & 3;
    const int g    = lane >> 5;
    const int lq   = lane & 31;
    const int bh = blockIdx.y, b = bh >> 3, h = bh & 7;
    const int q  = blockIdx.x * 128 + qw * 32 + lq;

    u32* const KH = lds + grp * 4864;
    u32* const KL = KH + 1152;
    u32* const VH = KH + 2304;
    u32* const VL = KH + 3584;

    const float SC = 0.125f * 1.44269504f;   // 1/sqrt(64) * log2(e)

    short8 qh[4], ql[4];
    {
        const size_t qb = ((size_t)bh * NN + q) * DKK;
        #pragma unroll
        for (int c = 0; c < 4; ++c) {
            const int d0 = c * 16 + g * 8;
            qh[c] = *(const short8*)&QH16[qb + d0];
            ql[c] = *(const short8*)&QL16[qb + d0];
        }
    }

    f32x16 acco[2];
    #pragma unroll
    for (int mf = 0; mf < 2; ++mf)
        #pragma unroll
        for (int r = 0; r < 16; ++r) acco[mf][r] = 0.f;
    float m_run = -1e30f, l_run = 0.f;   // raw (unscaled) domain

    const int gt   = tid & 255;
    const int skey = gt >> 3,  sdc = (gt & 7) * 8;
    const int vdk  = gt & 63,  vkg = (gt >> 6) * 8;
    const size_t kvrow = (size_t)bh * NN;
    const int kv0 = grp * 1024;

    for (int t = 0; t < 32; ++t) {
        const int kt = kv0 + t * 32;
        __syncthreads();
        {   // K tile: [key][dk] u16 -> LDS [key][36 u32]
            const size_t kb = (kvrow + kt + skey) * DKK + sdc;
            const int base = skey * 36 + sdc / 2;
            *(uint4*)&KH[base] = *(const uint4*)&KH16[kb];
            *(uint4*)&KL[base] = *(const uint4*)&KL16[kb];
        }
        {   // V^T tile: [bh][dk][n/2] u32 -> LDS [dk][20 u32]
            const size_t vb = ((size_t)bh * DKK + vdk) * (NN / 2) + ((kt + vkg) >> 1);
            const int base = vdk * 20 + vkg / 2;
            *(uint4*)&VH[base] = *(const uint4*)&VTH[vb];
            *(uint4*)&VL[base] = *(const uint4*)&VTL[vb];
        }
        __syncthreads();

        f32x16 s;
        #pragma unroll
        for (int r = 0; r < 16; ++r) s[r] = 0.f;
        #pragma unroll
        for (int c = 0; c < 4; ++c) {
            const int off = lq * 36 + c * 8 + g * 4;
            short8 kh = *(const short8*)&KH[off];
            short8 kl = *(const short8*)&KL[off];
            s = __builtin_amdgcn_mfma_f32_32x32x16_bf16(kh, qh[c], s, 0, 0, 0);
            s = __builtin_amdgcn_mfma_f32_32x32x16_bf16(kh, ql[c], s, 0, 0, 0);
            s = __builtin_amdgcn_mfma_f32_32x32x16_bf16(kl, qh[c], s, 0, 0, 0);
        }

        float mt = s[0];
        #pragma unroll
        for (int r = 1; r < 16; ++r) mt = fmaxf(mt, s[r]);
        mt = fmaxf(mt, __shfl_xor(mt, 32));
        const float mn = fmaxf(m_run, mt);
        const float alpha = exp2f((m_run - mn) * SC);
        const float nsc = -mn * SC;
        float p[16], ls = 0.f;
        #pragma unroll
        for (int r = 0; r < 16; ++r) { p[r] = exp2f(fmaf(s[r], SC, nsc)); ls += p[r]; }
        ls += __shfl_xor(ls, 32);
        l_run = l_run * alpha + ls;
        m_run = mn;
        #pragma unroll
        for (int mf = 0; mf < 2; ++mf)
            #pragma unroll
            for (int r = 0; r < 16; ++r) acco[mf][r] *= alpha;

        u32 wH[8];
        #pragma unroll
        for (int j = 0; j < 8; ++j) wH[j] = pk_bf2(p[2*j], p[2*j+1]);
        {
            u32 xH[8];
            #pragma unroll
            for (int j = 0; j < 8; ++j) xH[j] = __shfl_xor(wH[j], 32);
            short8 pfH[2];
            #pragma unroll
            for (int c = 0; c < 2; ++c) {
                union { u32 u[4]; short8 v; } FH;
                FH.u[0] = g ? xH[4*c + 2] : wH[4*c];
                FH.u[1] = g ? xH[4*c + 3] : wH[4*c + 1];
                FH.u[2] = g ? wH[4*c + 2] : xH[4*c];
                FH.u[3] = g ? wH[4*c + 3] : xH[4*c + 1];
                pfH[c] = FH.v;
            }
            #pragma unroll
            for (int mf = 0; mf < 2; ++mf)
                #pragma unroll
                for (int c = 0; c < 2; ++c) {
                    const int off = (mf * 32 + lq) * 20 + c * 8 + g * 4;
                    short8 vh = *(const short8*)&VH[off];
                    short8 vl = *(const short8*)&VL[off];
                    acco[mf] = __builtin_amdgcn_mfma_f32_32x32x16_bf16(vh, pfH[c], acco[mf], 0, 0, 0);
                    acco[mf] = __builtin_amdgcn_mfma_f32_32x32x16_bf16(vl, pfH[c], acco[mf], 0, 0, 0);
                }
        }
        {
            u32 wL[8];
            #pragma unroll
            for (int j = 0; j < 8; ++j) {
                float2 hf = upk_bf2(wH[j]);
                wL[j] = pk_bf2(p[2*j] - hf.x, p[2*j+1] - hf.y);
            }
            u32 xL[8];
            #pragma unroll
            for (int j = 0; j < 8; ++j) xL[j] = __shfl_xor(wL[j], 32);
            short8 pfL[2];
            #pragma unroll
            for (int c = 0; c < 2; ++c) {
                union { u32 u[4]; short8 v; } FL;
                FL.u[0] = g ? xL[4*c + 2] : wL[4*c];
                FL.u[1] = g ? xL[4*c + 3] : wL[4*c + 1];
                FL.u[2] = g ? wL[4*c + 2] : xL[4*c];
                FL.u[3] = g ? wL[4*c + 3] : xL[4*c + 1];
                pfL[c] = FL.v;
            }
            #pragma unroll
            for (int mf = 0; mf < 2; ++mf)
                #pragma unroll
                for (int c = 0; c < 2; ++c) {
                    const int off = (mf * 32 + lq) * 20 + c * 8 + g * 4;
                    short8 vh = *(const short8*)&VH[off];
                    acco[mf] = __builtin_amdgcn_mfma_f32_32x32x16_bf16(vh, pfL[c], acco[mf], 0, 0, 0);
                }
        }
    }

    __syncthreads();
    float* C  = (float*)lds;                // [4][64][33]
    float* ml = (float*)(lds + 8448);       // [4][32][2]
    if (grp == 1) {
        #pragma unroll
        for (int mf = 0; mf < 2; ++mf)
            #pragma unroll
            for (int qd = 0; qd < 4; ++qd) {
                const int dkb = mf * 32 + 8 * qd + 4 * g;
                #pragma unroll
                for (int e = 0; e < 4; ++e)
                    C[qw * 2112 + (dkb + e) * 33 + lq] = acco[mf][4*qd + e];
            }
        if (g == 0) {
            ml[qw * 64 + lq * 2]     = m_run;
            ml[qw * 64 + lq * 2 + 1] = l_run;
        }
    }
    __syncthreads();
    if (grp == 0) {
        const float m1 = ml[qw * 64 + lq * 2];
        const float l1 = ml[qw * 64 + lq * 2 + 1];
        const float mN = fmaxf(m_run, m1);
        const float a0 = exp2f((m_run - mN) * SC);
        const float a1 = exp2f((m1 - mN) * SC);
        const float inv = 1.f / (a0 * l_run + a1 * l1);
        const size_t rowb32 = ((size_t)b * NN + q) * 256;
        #pragma unroll
        for (int mf = 0; mf < 2; ++mf)
            #pragma unroll
            for (int qd = 0; qd < 4; ++qd) {
                const int dkb = mf * 32 + 8 * qd + 4 * g;
                float v0 = (a0 * acco[mf][4*qd+0] + a1 * C[qw * 2112 + (dkb+0) * 33 + lq]) * inv;
                float v1 = (a0 * acco[mf][4*qd+1] + a1 * C[qw * 2112 + (dkb+1) * 33 + lq]) * inv;
                float v2 = (a0 * acco[mf][4*qd+2] + a1 * C[qw * 2112 + (dkb+2) * 33 + lq]) * inv;
                float v3 = (a0 * acco[mf][4*qd+3] + a1 * C[qw * 2112 + (dkb+3) * 33 + lq]) * inv;
                u32 h0, l0, h1, l1b;
                split_pk(v0, v1, h0, l0);
                split_pk(v2, v3, h1, l1b);
                const size_t ci = rowb32 + ((h * DKK + dkb) >> 1);
                CtxH[ci]     = h0; CtxH[ci + 1] = h1;
                CtxL[ci]     = l0; CtxL[ci + 1] = l1b;
            }
    }
}

// ---------------------------------------------------------------------------
extern "C" void kernel_launch(void* const* d_in, const int* in_sizes, int n_in,
                              void* d_out, int out_size, void* d_ws, size_t ws_size,
                              hipStream_t stream) {
    const float* q  = (const float*)d_in[0];
    const float* k  = (const float*)d_in[1];
    const float* v  = (const float*)d_in[2];
    const float* Wq = (const float*)d_in[3];
    const float* bq = (const float*)d_in[4];
    const float* Wk = (const float*)d_in[5];
    const float* bk = (const float*)d_in[6];
    const float* Wv = (const float*)d_in[7];
    const float* bv = (const float*)d_in[8];
    const float* Wo = (const float*)d_in[9];
    const float* bo = (const float*)d_in[10];

    u32* W32 = (u32*)d_ws;
    const size_t M2 = 2097152;                 // u32 count of one [8192][256]
    u32* XqH = W32;                 u32* XqL = XqH + M2;
    u32* XkH = XqL + M2;            u32* XkL = XkH + M2;
    u32* XvH = XkL + M2;            u32* XvL = XvH + M2;
    u16* QH16 = (u16*)(XvL + M2);   u16* QL16 = QH16 + 4194304;
    u16* KH16 = QL16 + 4194304;     u16* KL16 = KH16 + 4194304;
    u32* VTH  = (u32*)(KL16 + 4194304);
    u32* VTL  = VTH + M2;
    u32* CtxH = VTL + M2;           u32* CtxL = CtxH + M2;
    u32* WTH  = CtxL + M2;          u32* WTL  = WTH + 4 * 131072;

    wsplit<<<dim3(128, 4), dim3(256), 0, stream>>>(Wq, Wk, Wv, Wo, WTH, WTL);
    xsplit<<<dim3(2048), dim3(256), 0, stream>>>(q, XqH, XqL);
    xsplit<<<dim3(2048), dim3(256), 0, stream>>>(k, XkH, XkL);
    xsplit<<<dim3(2048), dim3(256), 0, stream>>>(v, XvH, XvL);

    gemm_mfma<0><<<dim3(64, 4), dim3(256), 0, stream>>>(
        XqH, XqL, WTH, WTL, bq, QH16, QL16, nullptr, nullptr, nullptr, 0);
    gemm_mfma<0><<<dim3(64, 4), dim3(256), 0, stream>>>(
        XkH, XkL, WTH + 131072, WTL + 131072, bk, KH16, KL16, nullptr, nullptr, nullptr, 1);
    gemm_mfma<0><<<dim3(64, 4), dim3(256), 0, stream>>>(
        XvH, XvL, WTH + 2 * 131072, WTL + 2 * 131072, bv, nullptr, nullptr, VTH, VTL, nullptr, 2);

    attn_mfma<<<dim3(16, 32), dim3(512), 0, stream>>>(
        QH16, QL16, KH16, KL16, VTH, VTL, CtxH, CtxL);

    gemm_mfma<1><<<dim3(64, 4), dim3(256), 0, stream>>>(
        CtxH, CtxL, WTH + 3 * 131072, WTL + 3 * 131072, bo,
        nullptr, nullptr, nullptr, nullptr, (float*)d_out, 0);
}